// Round 3
// baseline (116.556 us; speedup 1.0000x reference)
//
#include <hip/hip_runtime.h>

// LocBlock2dNT: x (64,64,64,64) f32, w (256,64,16,16,16) f32
// out (64,256,16,16) f32 = relu( einsum('ncpqf,ocpqf->nopq', patches, w) / 32 )
// Block = (p, q, o-half): GEMM M=64(n) x N=128(o) x K=1024. Grid 512 = 2 blocks/CU.
// 3-deep global_load_lds pipeline, counted vmcnt(6), raw s_barrier.

typedef short bf16x8 __attribute__((ext_vector_type(8)));
typedef float f32x4  __attribute__((ext_vector_type(4)));

__device__ __forceinline__ short f2bf(float f) {
    union { float f; unsigned u; } v; v.f = f;
    return (short)((v.u + 0x7FFFu + ((v.u >> 16) & 1u)) >> 16);   // RNE
}

__device__ __forceinline__ bf16x8 pack8(f32x4 a, f32x4 b) {
    bf16x8 r;
    r[0] = f2bf(a[0]); r[1] = f2bf(a[1]); r[2] = f2bf(a[2]); r[3] = f2bf(a[3]);
    r[4] = f2bf(b[0]); r[5] = f2bf(b[1]); r[6] = f2bf(b[2]); r[7] = f2bf(b[3]);
    return r;
}

__device__ __forceinline__ void gload16(const void* g, void* l) {
    __builtin_amdgcn_global_load_lds(
        (const __attribute__((address_space(1))) void*)g,
        (__attribute__((address_space(3))) void*)l, 16, 0, 0);
}

__global__ __launch_bounds__(512, 4)
void locblock_mfma(const float* __restrict__ x, const float* __restrict__ w,
                   float* __restrict__ out) {
    // 3 buffers x [ A 8 KB | B 16 KB ] = 72 KB -> 2 blocks/CU (144 KB of 160)
    __shared__ __align__(16) char smem[3][24576];

    // XCD swizzle: 64 consecutive logical blocks per XCD; the two o-halves of
    // one (p,q) are adjacent -> same XCD -> A (x) reads dedup in L2.
    const int hw = blockIdx.x;
    const int lb = (hw & 7) * 64 + (hw >> 3);        // bijective, 512 % 8 == 0
    const int pq = lb >> 1, oh = lb & 1;
    const int p = pq >> 4, q = pq & 15;

    const int tid  = (int)threadIdx.x;
    const int lane = tid & 63;
    const int wv   = tid >> 6;                       // 0..7
    const int l15  = lane & 15;
    const int kq   = lane >> 4;                      // 0..3
    const int wr   = wv >> 2;                        // n-half  (32 rows)
    const int wc   = wv & 3;                         // o-quarter of 128 (32 cols)

    // ---- staging sources (t=0); advance 8192 floats (2 c's) per step ----
    // A: 512 chunks of 16B, chunk = tid -> (n = chunk>>3, pos = chunk&7).
    // Stored linearly; source chunk index = pos ^ (n&7) (swizzle on SOURCE).
    const int an   = tid >> 3;
    const int acfs = (tid & 7) ^ (an & 7);
    const float* asrc = x + (size_t)an * 262144u + (size_t)(acfs >> 2) * 4096u
                          + (size_t)(4 * p + (acfs & 3)) * 64u + (size_t)(4 * q);
    // B: 1024 chunks of 16B, 2 per thread, chunk = j*512 + tid.
    const float* bsrc[2];
#pragma unroll
    for (int j = 0; j < 2; ++j) {
        const int chunk = j * 512 + tid;
        const int ol  = chunk >> 3;                  // 0..127
        const int o   = oh * 128 + ol;
        const int cfs = (chunk & 7) ^ (ol & 7);
        bsrc[j] = w + (size_t)o * 262144u + (size_t)(cfs >> 2) * 4096u
                    + (size_t)p * 256u + (size_t)q * 16u + (size_t)((cfs & 3) * 4);
    }

    // ---- LDS fragment-read offsets (floats). Logical chunk 2kq+d of a row
    // is stored at position (2kq+d) ^ (row&7); row&7 == l15&7 for all frags.
    int aofs[2][2], bofs[2][2];
#pragma unroll
    for (int mf = 0; mf < 2; ++mf) {
        const int n = wr * 32 + mf * 16 + l15;
        aofs[mf][0] = (n * 8 + ((2 * kq)     ^ (l15 & 7))) * 4;
        aofs[mf][1] = (n * 8 + ((2 * kq + 1) ^ (l15 & 7))) * 4;
    }
#pragma unroll
    for (int nf = 0; nf < 2; ++nf) {
        const int ol = wc * 32 + nf * 16 + l15;
        bofs[nf][0] = 2048 + (ol * 8 + ((2 * kq)     ^ (l15 & 7))) * 4;
        bofs[nf][1] = 2048 + (ol * 8 + ((2 * kq + 1) ^ (l15 & 7))) * 4;
    }

    f32x4 acc[2][2];
#pragma unroll
    for (int mf = 0; mf < 2; ++mf)
#pragma unroll
        for (int nf = 0; nf < 2; ++nf)
            acc[mf][nf] = (f32x4){0.f, 0.f, 0.f, 0.f};

    auto stage = [&](int t, int buf) {
        char* base = smem[buf];
        const size_t toff = (size_t)t * 8192u;
        gload16(asrc + toff,    base + wv * 1024);                  // A
        gload16(bsrc[0] + toff, base + 8192 + wv * 1024);           // B j=0
        gload16(bsrc[1] + toff, base + 8192 + 8192 + wv * 1024);    // B j=1
    };

    auto compute = [&](int buf) {
        const float* Lb = (const float*)smem[buf];
        bf16x8 av[2], bv[2];
#pragma unroll
        for (int mf = 0; mf < 2; ++mf)
            av[mf] = pack8(*(const f32x4*)(Lb + aofs[mf][0]),
                           *(const f32x4*)(Lb + aofs[mf][1]));
#pragma unroll
        for (int nf = 0; nf < 2; ++nf)
            bv[nf] = pack8(*(const f32x4*)(Lb + bofs[nf][0]),
                           *(const f32x4*)(Lb + bofs[nf][1]));
#pragma unroll
        for (int mf = 0; mf < 2; ++mf)
#pragma unroll
            for (int nf = 0; nf < 2; ++nf)
                acc[mf][nf] = __builtin_amdgcn_mfma_f32_16x16x32_bf16(
                    av[mf], bv[nf], acc[mf][nf], 0, 0, 0);
    };

    // ---- 3-deep pipeline over 32 K-steps (3 loads/thread per stage) ----
    stage(0, 0);
    stage(1, 1);
    stage(2, 2);
#pragma unroll 1
    for (int t = 0; t < 29; ++t) {
        const int buf = t % 3;
        asm volatile("s_waitcnt vmcnt(6)" ::: "memory");   // stage t landed
        __builtin_amdgcn_s_barrier();
        compute(buf);
        asm volatile("s_waitcnt lgkmcnt(0)" ::: "memory"); // reads retired
        __builtin_amdgcn_s_barrier();
        stage(t + 3, buf);
    }
    // drain: t = 29, 30, 31
    asm volatile("s_waitcnt vmcnt(6)" ::: "memory");
    __builtin_amdgcn_s_barrier();
    compute(2);
    asm volatile("s_waitcnt vmcnt(3)" ::: "memory");
    __builtin_amdgcn_s_barrier();
    compute(0);
    asm volatile("s_waitcnt vmcnt(0)" ::: "memory");
    __builtin_amdgcn_s_barrier();
    compute(1);

    // ---- epilogue: C/D layout col=lane&15 (=o frag), row=kq*4+j (=n frag) ----
    const float scale = 0.03125f;                    // 1/sqrt(16*64)
    const int rbase = kq * 4;
#pragma unroll
    for (int mf = 0; mf < 2; ++mf)
#pragma unroll
        for (int nf = 0; nf < 2; ++nf) {
            const int o = oh * 128 + wc * 32 + nf * 16 + l15;
#pragma unroll
            for (int j = 0; j < 4; ++j) {
                const int n = wr * 32 + mf * 16 + rbase + j;
                const float v = acc[mf][nf][j] * scale;
                out[(size_t)n * 65536u + (size_t)o * 256u + (size_t)pq] =
                    fmaxf(v, 0.0f);
            }
        }
}

extern "C" void kernel_launch(void* const* d_in, const int* in_sizes, int n_in,
                              void* d_out, int out_size, void* d_ws, size_t ws_size,
                              hipStream_t stream) {
    const float* x = (const float*)d_in[0];
    const float* w = (const float*)d_in[1];
    float* out = (float*)d_out;
    locblock_mfma<<<dim3(512), dim3(512), 0, stream>>>(x, w, out);
}

// Round 4
// 90.842 us; speedup vs baseline: 1.2831x; 1.2831x over previous
//
#include <hip/hip_runtime.h>

// LocBlock2dNT: x (64,64,64,64) f32, w (256,64,16,16,16) f32
// out (64,256,16,16) f32 = relu( einsum('ncpqf,ocpqf->nopq', patches, w) / 32 )
//
// Kernel 1: block = (p, q-pair, o-half), grid 256. Per wave: one q, 32 o's.
//   w staged as 128-B contiguous runs, x as 32-B runs, via global_load_lds
//   (3-deep, counted vmcnt). Result (relu-scaled) -> ws in [pq][o][n] layout
//   with contiguous dwordx4 stores.
// Kernel 2: transpose ws [pq][o][n] -> out [n][o][pq] (16 MB, coalesced).

typedef short bf16x8 __attribute__((ext_vector_type(8)));
typedef float f32x4  __attribute__((ext_vector_type(4)));

__device__ __forceinline__ short f2bf(float f) {
    union { float f; unsigned u; } v; v.f = f;
    return (short)((v.u + 0x7FFFu + ((v.u >> 16) & 1u)) >> 16);   // RNE
}

__device__ __forceinline__ bf16x8 pack8(f32x4 a, f32x4 b) {
    bf16x8 r;
    r[0] = f2bf(a[0]); r[1] = f2bf(a[1]); r[2] = f2bf(a[2]); r[3] = f2bf(a[3]);
    r[4] = f2bf(b[0]); r[5] = f2bf(b[1]); r[6] = f2bf(b[2]); r[7] = f2bf(b[3]);
    return r;
}

__device__ __forceinline__ void gload16(const void* g, void* l) {
    __builtin_amdgcn_global_load_lds(
        (const __attribute__((address_space(1))) void*)g,
        (__attribute__((address_space(3))) void*)l, 16, 0, 0);
}

// ---------------------------------------------------------------- kernel 1
__global__ __launch_bounds__(512)
void locblock_gemm(const float* __restrict__ x, const float* __restrict__ w,
                   float* __restrict__ ws) {
    // 3 x [ x-tile 16 KB | w-tile 32 KB ] = 144 KB
    __shared__ __align__(16) char smem[3][49152];

    // XCD swizzle: 32 consecutive logical blocks (2 full p's) per XCD ->
    // q-neighbor x half-lines and oh-pair x reads merge/dedup in L2.
    const int hw = blockIdx.x;
    const int lb = (hw & 7) * 32 + (hw >> 3);        // bijective, 256 % 8 == 0
    const int p  = lb >> 4;
    const int q2 = (lb >> 1) & 7;                    // q-pair index (q = 2*q2+qw)
    const int oh = lb & 1;                           // o half (128 o's)

    const int tid  = (int)threadIdx.x;
    const int lane = tid & 63;
    const int wv   = tid >> 6;                       // 0..7
    const int l15  = lane & 15;
    const int kq   = lane >> 4;                      // 0..3
    const int qw   = wv & 1;                         // wave's q within pair
    const int nc   = wv >> 1;                        // wave's o-quarter (32 o)

    // ---- staging sources (chunk u = c*8 + fr*2 + h for x; c*8 + h8 for w;
    //      LDS slot s holds source chunk u = s ^ (row & 15)) ----
    const float* xsrc[2];
#pragma unroll
    for (int j = 0; j < 2; ++j) {
        const int id = j * 512 + tid;                // 1024 chunks of 16 B
        const int n = id >> 4, s = id & 15;
        const int u = s ^ (n & 15);
        xsrc[j] = x + (size_t)n * 262144u + (size_t)(u >> 3) * 4096u
                    + (size_t)(4 * p + ((u >> 1) & 3)) * 64u
                    + (size_t)(q2 * 8 + (u & 1) * 4);
    }
    const float* wsrc[4];
#pragma unroll
    for (int j = 0; j < 4; ++j) {
        const int id = j * 512 + tid;                // 2048 chunks of 16 B
        const int ol = id >> 4, s = id & 15;
        const int u = s ^ (ol & 15);
        wsrc[j] = w + (size_t)(oh * 128 + ol) * 262144u + (size_t)(u >> 3) * 4096u
                    + (size_t)p * 256u + (size_t)(q2 * 32) + (size_t)((u & 7) * 4);
    }

    // ---- fragment LDS byte offsets ----
    int aoff[4][2], boff[2][2];
#pragma unroll
    for (int mf = 0; mf < 4; ++mf) {
        const int n = mf * 16 + l15;
        const int v1 = (kq >> 1) * 8 + (kq & 1) * 4 + qw;      // c*8 + fr*2 + h
        aoff[mf][0] = n * 256 + ((v1       ^ l15) * 16);
        aoff[mf][1] = n * 256 + (((v1 + 2) ^ l15) * 16);       // fr+1
    }
#pragma unroll
    for (int nf = 0; nf < 2; ++nf) {
        const int ol = nc * 32 + nf * 16 + l15;
        const int u1 = (kq >> 1) * 8 + qw * 4 + (kq & 1) * 2;  // c*8 + h8
        boff[nf][0] = 16384 + ol * 256 + ((u1       ^ l15) * 16);
        boff[nf][1] = 16384 + ol * 256 + (((u1 + 1) ^ l15) * 16);
    }

    f32x4 acc[4][2];
#pragma unroll
    for (int mf = 0; mf < 4; ++mf)
#pragma unroll
        for (int nf = 0; nf < 2; ++nf)
            acc[mf][nf] = (f32x4){0.f, 0.f, 0.f, 0.f};

    auto stage = [&](int t, int buf) {
        char* base = smem[buf];
        const size_t toff = (size_t)t * 8192u;       // advance 2 c's per step
#pragma unroll
        for (int j = 0; j < 2; ++j)
            gload16(xsrc[j] + toff, base + j * 8192 + wv * 1024);
#pragma unroll
        for (int j = 0; j < 4; ++j)
            gload16(wsrc[j] + toff, base + 16384 + j * 8192 + wv * 1024);
    };

    auto compute = [&](int buf) {
        const char* Lb = smem[buf];
        bf16x8 av[4], bv[2];
#pragma unroll
        for (int mf = 0; mf < 4; ++mf)
            av[mf] = pack8(*(const f32x4*)(Lb + aoff[mf][0]),
                           *(const f32x4*)(Lb + aoff[mf][1]));
#pragma unroll
        for (int nf = 0; nf < 2; ++nf)
            bv[nf] = pack8(*(const f32x4*)(Lb + boff[nf][0]),
                           *(const f32x4*)(Lb + boff[nf][1]));
#pragma unroll
        for (int mf = 0; mf < 4; ++mf)
#pragma unroll
            for (int nf = 0; nf < 2; ++nf)
                acc[mf][nf] = __builtin_amdgcn_mfma_f32_16x16x32_bf16(
                    av[mf], bv[nf], acc[mf][nf], 0, 0, 0);
    };

    // ---- 3-deep pipeline over 32 K-steps (6 loads/thread per stage) ----
    stage(0, 0);
    stage(1, 1);
    stage(2, 2);
#pragma unroll 1
    for (int t = 0; t < 29; ++t) {
        const int buf = t % 3;
        asm volatile("s_waitcnt vmcnt(12)" ::: "memory");  // stage t landed
        __builtin_amdgcn_s_barrier();
        compute(buf);
        asm volatile("s_waitcnt lgkmcnt(0)" ::: "memory"); // reads retired
        __builtin_amdgcn_s_barrier();
        stage(t + 3, buf);
    }
    asm volatile("s_waitcnt vmcnt(12)" ::: "memory");
    __builtin_amdgcn_s_barrier();
    compute(2);                                            // t = 29
    asm volatile("s_waitcnt vmcnt(6)" ::: "memory");
    __builtin_amdgcn_s_barrier();
    compute(0);                                            // t = 30
    asm volatile("s_waitcnt vmcnt(0)" ::: "memory");
    __builtin_amdgcn_s_barrier();
    compute(1);                                            // t = 31

    // ---- epilogue: relu-scale, store to ws[pq][o][n] (16-B contiguous) ----
    const float scale = 0.03125f;                    // 1/sqrt(16*64)
    const int pq = p * 16 + q2 * 2 + qw;
#pragma unroll
    for (int mf = 0; mf < 4; ++mf)
#pragma unroll
        for (int nf = 0; nf < 2; ++nf) {
            const int o  = oh * 128 + nc * 32 + nf * 16 + l15;
            const int n0 = mf * 16 + kq * 4;         // C/D row = kq*4 + j
            f32x4 r;
#pragma unroll
            for (int j = 0; j < 4; ++j)
                r[j] = fmaxf(acc[mf][nf][j] * scale, 0.0f);
            *(f32x4*)(ws + (size_t)pq * 16384u + (size_t)o * 64u + n0) = r;
        }
}

// ---------------------------------------------------------------- kernel 2
__global__ __launch_bounds__(256)
void finish_transpose(const float* __restrict__ ws, float* __restrict__ out) {
    __shared__ float tile[256 * 68];                 // pad 68 keeps 16B align
    const int o = blockIdx.x;
    const int t = (int)threadIdx.x;

#pragma unroll
    for (int it = 0; it < 16; ++it) {
        const int chunk = it * 256 + t;              // 4096 chunks of 16 B
        const int pq = chunk >> 4, ng = chunk & 15;
        const f32x4 v = *(const f32x4*)(ws + (size_t)pq * 16384u
                                           + (size_t)o * 64u + ng * 4);
        *(f32x4*)&tile[pq * 68 + ng * 4] = v;
    }
    __syncthreads();

    const int n = t >> 2, pqq = t & 3;
#pragma unroll
    for (int i = 0; i < 16; ++i) {
        const int pq0 = i * 16 + pqq * 4;
        f32x4 r;
#pragma unroll
        for (int k = 0; k < 4; ++k)
            r[k] = tile[(pq0 + k) * 68 + n];
        *(f32x4*)(out + (size_t)n * 65536u + (size_t)o * 256u + pq0) = r;
    }
}

extern "C" void kernel_launch(void* const* d_in, const int* in_sizes, int n_in,
                              void* d_out, int out_size, void* d_ws, size_t ws_size,
                              hipStream_t stream) {
    const float* x = (const float*)d_in[0];
    const float* w = (const float*)d_in[1];
    float* out = (float*)d_out;
    float* ws  = (float*)d_ws;                       // needs 16 MB (ws ~1 GB)
    locblock_gemm<<<dim3(256), dim3(512), 0, stream>>>(x, w, ws);
    finish_transpose<<<dim3(256), dim3(256), 0, stream>>>(ws, out);
}